// Round 9
// baseline (2427.528 us; speedup 1.0000x reference)
//
#include <hip/hip_runtime.h>
#include <hip/hip_bf16.h>

#define SEQ    4096
#define SCALE  0.125f

typedef __attribute__((ext_vector_type(8))) short s8v;
typedef __attribute__((ext_vector_type(8))) unsigned short u8v;
typedef __attribute__((ext_vector_type(4))) float f4v;

__device__ __forceinline__ unsigned short f2bf(float f){
  unsigned int u = __builtin_bit_cast(unsigned int, f);
  u += 0x7FFFu + ((u >> 16) & 1u);
  return (unsigned short)(u >> 16);
}

typedef const __attribute__((address_space(1))) unsigned int gl_uint;
typedef __attribute__((address_space(3))) unsigned int lds_uint;

__device__ __forceinline__ void gload_lds16(const unsigned short* g, unsigned short* l){
  __builtin_amdgcn_global_load_lds((gl_uint*)g, (lds_uint*)l, 16, 0, 0);
}

#define MM(a,b,c) __builtin_amdgcn_mfma_f32_16x16x32_bf16(a,b,c,0,0,0)
#define BAR() __builtin_amdgcn_s_barrier()
#define SB0() __builtin_amdgcn_sched_barrier(0)
#define LGKM0() do{ asm volatile("s_waitcnt lgkmcnt(0)" ::: "memory"); SB0(); }while(0)
#define VMW(n) asm volatile("s_waitcnt vmcnt(" #n ")" ::: "memory")

__device__ __forceinline__ void mfmaH0(const s8v (&A)[8], const s8v (&B)[4], f4v (&acc)[8][4]){
#pragma unroll
  for (int m = 0; m < 4; m++)
#pragma unroll
    for (int n = 0; n < 4; n++) acc[m][n] = MM(A[m], B[n], acc[m][n]);
}
__device__ __forceinline__ void mfmaH1(const s8v (&A)[8], const s8v (&B)[4], f4v (&acc)[8][4]){
#pragma unroll
  for (int m = 4; m < 8; m++)
#pragma unroll
    for (int n = 0; n < 4; n++) acc[m][n] = MM(A[m], B[n], acc[m][n]);
}

// ================ mainloop (2-SLOT ring, 64 KiB -> 2 blocks/CU):
// A+B per slot = 32 KB, 2 slots. One barrier per K-tile, reg-banked frags.
// BODY(t): LGKM0 (drain my frag(t) reads -- they're this body's MFMA inputs;
//          required before STG(t+2) overwrites slot t&1);
//          VMW(0) (stage(t+1) done; only 4 ops, issued one full body ago);
//          BAR (collective: all waves' slot-t reads done, tile t+1 resident);
//          STG(t+2) -> slot t&1 (dead); ds_read frags(t+1) from slot (t+1)&1
//          interleaved with MFMA(t) halves.
// Swizzle identical to round-4-verified (SQ_LDS_BANK_CONFLICT == 0).
__device__ __forceinline__ void mainloop_ab(
    const unsigned short* __restrict__ Ag,
    const unsigned short* __restrict__ Bg,
    int bm, int bn, f4v (&acc)[8][4])
{
  __shared__ __align__(16) unsigned short lds[32768];   // 64 KiB
  const int tid  = threadIdx.x;
  const int wave = tid >> 6, lane = tid & 63;
  const int quad = lane >> 4, l16 = lane & 15;
  const int wmi  = wave >> 2, wni = wave & 3;
  const char* ldsc = (const char*)lds;

  const int c16   = (quad ^ ((l16 >> 1) & 3)) * 16;     // byte chunk offset
  const int abase = (wmi * 128 + l16) * 64 + c16;       // bytes within slot
  const int bbase = 16384 + (wni * 64 + l16) * 64 + c16;

  const int schunk = (((tid & 3) ^ ((tid >> 3) & 3)) * 8);
  const unsigned short* aS = Ag + (size_t)(bm + (tid >> 2)) * 1024 + schunk;
  const unsigned short* bS = Bg + (size_t)(bn + (tid >> 2)) * 1024 + schunk;
  unsigned short* ldsw = lds + wave * 512;   // wave-uniform gload_lds base

#define STG_A(t_) do{ unsigned short* d_ = ldsw + ((t_) & 1) * 16384; \
    const unsigned short* s_ = aS + (t_) * 32; \
    gload_lds16(s_, d_); gload_lds16(s_ + 128 * 1024, d_ + 4096); }while(0)
#define STG_B(t_) do{ unsigned short* d_ = ldsw + ((t_) & 1) * 16384 + 8192; \
    const unsigned short* s_ = bS + (t_) * 32; \
    gload_lds16(s_, d_); gload_lds16(s_ + 128 * 1024, d_ + 4096); }while(0)

#define LD_B4(NB, base_) do{ \
    NB[0] = *(const s8v*)((base_) + bbase);        NB[1] = *(const s8v*)((base_) + bbase + 1024); \
    NB[2] = *(const s8v*)((base_) + bbase + 2048); NB[3] = *(const s8v*)((base_) + bbase + 3072); }while(0)
#define LD_A4LO(NA, base_) do{ \
    NA[0] = *(const s8v*)((base_) + abase);        NA[1] = *(const s8v*)((base_) + abase + 1024); \
    NA[2] = *(const s8v*)((base_) + abase + 2048); NA[3] = *(const s8v*)((base_) + abase + 3072); }while(0)
#define LD_A4HI(NA, base_) do{ \
    NA[4] = *(const s8v*)((base_) + abase + 4096); NA[5] = *(const s8v*)((base_) + abase + 5120); \
    NA[6] = *(const s8v*)((base_) + abase + 6144); NA[7] = *(const s8v*)((base_) + abase + 7168); }while(0)

  s8v A0[8], B0[4], A1[8], B1[4];

  // prologue: stage tiles 0,1 (8 ops); retire tile 0 (VMW(4)); read its frags
  STG_A(0); STG_B(0); STG_A(1); STG_B(1);
  VMW(4); BAR();
  LD_B4(B0, ldsc); LD_A4LO(A0, ldsc); LD_A4HI(A0, ldsc);

#define BODY(T_, CA, CB, NA, NB, DOSTG) do{ \
    LGKM0(); VMW(0); BAR(); SB0(); \
    if (DOSTG){ STG_A((T_) + 2); STG_B((T_) + 2); } \
    { const char* nb_ = ldsc + ((((T_) + 1) & 1) << 15); \
      LD_B4(NB, nb_); LD_A4LO(NA, nb_); \
      __builtin_amdgcn_s_setprio(1); mfmaH0(CA, CB, acc); __builtin_amdgcn_s_setprio(0); \
      LD_A4HI(NA, nb_); \
      __builtin_amdgcn_s_setprio(1); mfmaH1(CA, CB, acc); __builtin_amdgcn_s_setprio(0); } \
  }while(0)

  for (int t = 0; t < 30; t += 2){
    BODY(t,     A0, B0, A1, B1, 1);            // stages t+2 (<= 31)
    BODY(t + 1, A1, B1, A0, B0, (t + 1) <= 29);
  }
  BODY(30, A0, B0, A1, B1, 0);                 // reads frags(31)
  // tile 31 (frags in A1/B1; compiler inserts the lgkm wait)
  __builtin_amdgcn_s_setprio(1);
  mfmaH0(A1, B1, acc); mfmaH1(A1, B1, acc);
  __builtin_amdgcn_s_setprio(0);

#undef BODY
#undef LD_B4
#undef LD_A4LO
#undef LD_A4HI
#undef STG_A
#undef STG_B
}

// ================ mainloop variant 2 (round-7 verified on gemm_final):
// A-only LDS ring (64 KiB); B from global in fragment-packed layout.
__device__ __forceinline__ void mainloop_apk(
    const unsigned short* __restrict__ Ag,
    const unsigned short* __restrict__ Bpk,
    int bm, int bn, f4v (&acc)[8][4])
{
  __shared__ __align__(16) unsigned short lds[32768];   // 64 KiB, A-only
  const int tid  = threadIdx.x;
  const int wave = tid >> 6, lane = tid & 63;
  const int quad = lane >> 4, l16 = lane & 15;
  const int wmi  = wave >> 2, wni = wave & 3;
  const char* ldsc = (const char*)lds;

  const int c16   = (quad ^ ((l16 >> 1) & 3)) * 16;
  const int abase = (wmi * 128 + l16) * 64 + c16;

  const int schunk = (((tid & 3) ^ ((tid >> 3) & 3)) * 8);
  const unsigned short* aS = Ag + (size_t)(bm + (tid >> 2)) * 1024 + schunk;
  unsigned short* ldsw = lds + wave * 512;

  const unsigned short* bP = Bpk + ((size_t)((bn >> 4) + wni * 4) * 2048 + lane) * 8;

#define STG_A2(t_) do{ unsigned short* d_ = ldsw + ((t_) & 3) * 8192; \
    const unsigned short* s_ = aS + (t_) * 32; \
    gload_lds16(s_, d_); gload_lds16(s_ + 128 * 1024, d_ + 4096); }while(0)

#define LDB2(t_, BN) do{ \
    BN[0] = *(const s8v*)(bP +         (t_) * 512); \
    BN[1] = *(const s8v*)(bP + 16384 + (t_) * 512); \
    BN[2] = *(const s8v*)(bP + 32768 + (t_) * 512); \
    BN[3] = *(const s8v*)(bP + 49152 + (t_) * 512); }while(0)

#define LD2_A4LO(NA, base_) do{ const char* p_ = (base_); \
    NA[0] = *(const s8v*)(p_ + abase);        NA[1] = *(const s8v*)(p_ + abase + 1024); \
    NA[2] = *(const s8v*)(p_ + abase + 2048); NA[3] = *(const s8v*)(p_ + abase + 3072); }while(0)
#define LD2_A4HI(NA, base_) do{ const char* p_ = (base_); \
    NA[4] = *(const s8v*)(p_ + abase + 4096); NA[5] = *(const s8v*)(p_ + abase + 5120); \
    NA[6] = *(const s8v*)(p_ + abase + 6144); NA[7] = *(const s8v*)(p_ + abase + 7168); }while(0)

  s8v A0[8], B0[4], A1[8], B1[4];

  STG_A2(0); STG_A2(1); STG_A2(2);
  LDB2(0, B0);
  VMW(8); BAR();
  LD2_A4LO(A0, ldsc); LD2_A4HI(A0, ldsc);

#define BODY2(T_, CA, CB, NA, NB, DOSTG, DOLD) do{ \
    SB0(); VMW(6); BAR(); SB0(); \
    if (DOSTG) STG_A2((T_) + 3); \
    if (DOLD)  LDB2((T_) + 1, NB); \
    if (DOLD)  LD2_A4LO(NA, ldsc + ((((T_) + 1) & 3) << 14)); \
    __builtin_amdgcn_s_setprio(1); mfmaH0(CA, CB, acc); __builtin_amdgcn_s_setprio(0); \
    if (DOLD)  LD2_A4HI(NA, ldsc + ((((T_) + 1) & 3) << 14)); \
    __builtin_amdgcn_s_setprio(1); mfmaH1(CA, CB, acc); __builtin_amdgcn_s_setprio(0); \
  }while(0)

  for (int t = 0; t < 28; t += 2){
    BODY2(t,     A0, B0, A1, B1, 1, 1);
    BODY2(t + 1, A1, B1, A0, B0, 1, 1);
  }
  BODY2(28, A0, B0, A1, B1, 1, 1);
  BODY2(29, A1, B1, A0, B0, 0, 1);
  BODY2(30, A0, B0, A1, B1, 0, 1);
  BODY2(31, A1, B1, A0, B0, 0, 0);

#undef BODY2
#undef LD2_A4LO
#undef LD2_A4HI
#undef LDB2
#undef STG_A2
}

// ---------------- qkv GEMM (fused q-softmax + k-exp), 256x256 tile, 2 blocks/CU
__global__ __launch_bounds__(512, 4) void qkv_gemm(
    const unsigned short* __restrict__ A,
    const unsigned short* __restrict__ Bt,
    unsigned short* __restrict__ qt,
    unsigned short* __restrict__ kt,
    unsigned short* __restrict__ vb)
{
  const int id  = blockIdx.x;
  const int swz = (id & 7) * 96 + (id >> 3);     // 768 blocks, bijective XCD swizzle
  const int bm  = (swz / 12) * 256, bn = (swz % 12) * 256;

  f4v acc[8][4];
#pragma unroll
  for (int i = 0; i < 8; i++)
#pragma unroll
    for (int j = 0; j < 4; j++) acc[i][j] = (f4v){0.f,0.f,0.f,0.f};

  mainloop_ab(A, Bt, bm, bn, acc);

  const int tid = threadIdx.x;
  const int wave = tid >> 6, lane = tid & 63;
  const int quad = lane >> 4, l16 = lane & 15;
  const int wmi = wave >> 2, wni = wave & 3;
  const int colbase = bn + wni * 64;             // 64-aligned -> one head per wave
  const int rowbase = bm + wmi * 128;
  const int sec = colbase >> 10;                 // 0=q 1=k 2=v (wave-uniform)

  if (sec == 2){
#pragma unroll
    for (int nf = 0; nf < 4; nf++){
      int vc = colbase + nf * 16 + l16 - 2048;
#pragma unroll
      for (int mf = 0; mf < 8; mf++){
        int row = rowbase + mf * 16 + quad * 4;
#pragma unroll
        for (int r = 0; r < 4; r++)
          vb[(size_t)(row + r) * 1024 + vc] = f2bf(acc[mf][nf][r]);
      }
    }
    return;
  }

  if (sec == 0){
    // fused softmax over d (wave's 64 cols = full head)
#pragma unroll
    for (int mf = 0; mf < 8; mf++){
#pragma unroll
      for (int r = 0; r < 4; r++){
        float m = fmaxf(fmaxf(acc[mf][0][r], acc[mf][1][r]),
                        fmaxf(acc[mf][2][r], acc[mf][3][r]));
        for (int off = 8; off; off >>= 1) m = fmaxf(m, __shfl_xor(m, off));
        m *= SCALE;
        float e0 = __expf(acc[mf][0][r] * SCALE - m);
        float e1 = __expf(acc[mf][1][r] * SCALE - m);
        float e2 = __expf(acc[mf][2][r] * SCALE - m);
        float e3 = __expf(acc[mf][3][r] * SCALE - m);
        float s = (e0 + e1) + (e2 + e3);
        for (int off = 8; off; off >>= 1) s += __shfl_xor(s, off);
        float inv = 1.f / s;
        acc[mf][0][r] = e0 * inv; acc[mf][1][r] = e1 * inv;
        acc[mf][2][r] = e2 * inv; acc[mf][3][r] = e3 * inv;
      }
    }
#pragma unroll
    for (int nf = 0; nf < 4; nf++){
      int col = colbase + nf * 16 + l16;
      int h = (col >> 6) & 15, de = col & 63;
#pragma unroll
      for (int mf = 0; mf < 8; mf++){
        int row = rowbase + mf * 16 + quad * 4;
        int bb = row >> 12, nl = row & 4095;
        ushort4 o;
        o.x = f2bf(acc[mf][nf][0]); o.y = f2bf(acc[mf][nf][1]);
        o.z = f2bf(acc[mf][nf][2]); o.w = f2bf(acc[mf][nf][3]);
        *(ushort4*)&qt[(((size_t)bb * 16 + h) * 64 + de) * SEQ + nl] = o;
      }
    }
  } else {
    // k: exp per element; normalizer recovered in ctx2 (q cols sum to 1)
#pragma unroll
    for (int nf = 0; nf < 4; nf++){
      int col = colbase + nf * 16 + l16;
      int h = (col >> 6) & 15, de = col & 63;
#pragma unroll
      for (int mf = 0; mf < 8; mf++){
        int row = rowbase + mf * 16 + quad * 4;
        int bb = row >> 12, nl = row & 4095;
        ushort4 o;
        o.x = f2bf(__expf(acc[mf][nf][0])); o.y = f2bf(__expf(acc[mf][nf][1]));
        o.z = f2bf(__expf(acc[mf][nf][2])); o.w = f2bf(__expf(acc[mf][nf][3]));
        *(ushort4*)&kt[(((size_t)bb * 16 + h) * 64 + de) * SEQ + nl] = o;
      }
    }
  }
}

// ---------------- final batched GEMM: out[b] = vb[b] @ ctx2^T + bias (round-7 form)
__global__ __launch_bounds__(512, 2) void gemm_final(
    const unsigned short* __restrict__ A,
    const unsigned short* __restrict__ C2pk,
    float* __restrict__ Cf,
    const float* __restrict__ bias)
{
  const int id  = blockIdx.x;
  const int swz = (id & 7) * 32 + (id >> 3);     // 256 blocks, bijective XCD swizzle
  const int bm  = (swz >> 2) * 256, bn = (swz & 3) * 256;
  const unsigned short* Bpk = C2pk + (size_t)(bm >> 12) * 1024 * 1024;

  f4v acc[8][4];
#pragma unroll
  for (int i = 0; i < 8; i++)
#pragma unroll
    for (int j = 0; j < 4; j++) acc[i][j] = (f4v){0.f,0.f,0.f,0.f};

  mainloop_apk(A, Bpk, bm, bn, acc);

  const int tid = threadIdx.x;
  const int wave = tid >> 6, lane = tid & 63;
  const int quad = lane >> 4, l16 = lane & 15;
  const int wmi = wave >> 2, wni = wave & 3;

#pragma unroll
  for (int nf = 0; nf < 4; nf++){
    int col = bn + wni * 64 + nf * 16 + l16;
    float bv = bias[col];
#pragma unroll
    for (int mf = 0; mf < 8; mf++){
      int row = bm + wmi * 128 + mf * 16 + quad * 4;
#pragma unroll
      for (int r = 0; r < 4; r++)
        Cf[(size_t)(row + r) * 1024 + col] = acc[mf][nf][r] + bv;
    }
  }
}

// ---------------- fp32 -> bf16 elementwise (4/thread)
__global__ void cvt_f32_bf16(const float4* __restrict__ in, ushort4* __restrict__ outp){
  int i = blockIdx.x * 256 + threadIdx.x;
  float4 v = in[i];
  ushort4 o;
  o.x = f2bf(v.x); o.y = f2bf(v.y); o.z = f2bf(v.z); o.w = f2bf(v.w);
  outp[i] = o;
}

// ---------------- transpose + cvt: in[R,C] fp32 -> out[C,R] bf16  (for qkv's B^T)
__global__ __launch_bounds__(256) void transpose_cvt(const float* __restrict__ in,
                                                     unsigned short* __restrict__ outp,
                                                     int R, int C){
  __shared__ float tile[64][65];
  int r0 = blockIdx.y * 64, c0 = blockIdx.x * 64;
  int t = threadIdx.x;
  for (int i = t; i < 4096; i += 256){ int r = i >> 6, c = i & 63;
    tile[r][c] = in[(size_t)(r0 + r) * C + c0 + c]; }
  __syncthreads();
  for (int i = t; i < 4096; i += 256){ int c = i >> 6, r = i & 63;
    outp[(size_t)(c0 + c) * R + r0 + r] = f2bf(tile[r][c]); }
}

// ---------------- ctx partial: ctxp[bh*4+chunk][d*64+e] = sum_{n in chunk} qt[d,n] kt[e,n]
__global__ __launch_bounds__(256) void ctx_partial(const unsigned short* __restrict__ qt,
                                                   const unsigned short* __restrict__ kt,
                                                   float* __restrict__ ctxp){
  __shared__ float red[4096];
  int bh = blockIdx.x >> 2, ch = blockIdx.x & 3;
  int t = threadIdx.x, wave = t >> 6, lane = t & 63, quad = lane >> 4, l16 = lane & 15;
  const unsigned short* qb = qt + (size_t)bh * 64 * SEQ;
  const unsigned short* kb = kt + (size_t)bh * 64 * SEQ;
  f4v acc[4][4];
#pragma unroll
  for (int i = 0; i < 4; i++)
#pragma unroll
    for (int j = 0; j < 4; j++) acc[i][j] = (f4v){0.f,0.f,0.f,0.f};
  int ns = ch * 1024 + wave * 256;
  for (int n0 = ns; n0 < ns + 256; n0 += 32){
    s8v af[4], bf[4];
#pragma unroll
    for (int mt = 0; mt < 4; mt++) af[mt] = *(const s8v*)&qb[(size_t)(mt*16 + l16) * SEQ + n0 + quad*8];
#pragma unroll
    for (int nt = 0; nt < 4; nt++) bf[nt] = *(const s8v*)&kb[(size_t)(nt*16 + l16) * SEQ + n0 + quad*8];
#pragma unroll
    for (int mt = 0; mt < 4; mt++)
#pragma unroll
      for (int nt = 0; nt < 4; nt++)
        acc[mt][nt] = __builtin_amdgcn_mfma_f32_16x16x32_bf16(af[mt], bf[nt], acc[mt][nt], 0, 0, 0);
  }
  for (int i = t; i < 4096; i += 256) red[i] = 0.f;
  __syncthreads();
  for (int w = 0; w < 4; w++){
    if (wave == w){
#pragma unroll
      for (int mt = 0; mt < 4; mt++)
#pragma unroll
        for (int nt = 0; nt < 4; nt++)
#pragma unroll
          for (int r = 0; r < 4; r++)
            red[(mt*16 + quad*4 + r) * 64 + nt*16 + l16] += acc[mt][nt][r];
    }
    __syncthreads();
  }
  float* cp = ctxp + (size_t)blockIdx.x * 4096;
  for (int i = t; i < 4096; i += 256) cp[i] = red[i];
}

// ---------------- ctx2: fragment-packed B for gemm_final (round-7 form).
__global__ __launch_bounds__(256) void ctx2_kernel(const float* __restrict__ ctxp,
                                                   const float* __restrict__ w_out,
                                                   unsigned short* __restrict__ ctx2t){
  __shared__ float ctxs[4096];
  __shared__ float inv_s[64];
  int bh = blockIdx.x >> 4, fc = blockIdx.x & 15;
  int b = bh >> 4, h = bh & 15;
  int t = threadIdx.x;
  int fl = t & 63, dg = t >> 6;
  int f = fc * 64 + fl;
  for (int i = t; i < 4096; i += 256){
    const float* p = ctxp + (size_t)bh * 4 * 4096 + i;
    ctxs[i] = (p[0] + p[4096]) + (p[8192] + p[12288]);
  }
  __syncthreads();
  if (t < 64){
    float s = 0.f;
#pragma unroll
    for (int d = 0; d < 64; d++) s += ctxs[d * 64 + t];
    inv_s[t] = 1.f / s;
  }
  __syncthreads();
  float acc[16];
#pragma unroll
  for (int i = 0; i < 16; i++) acc[i] = 0.f;
  for (int e = 0; e < 64; e++){
    float w = w_out[(size_t)(h * 64 + e) * 1024 + f] * inv_s[e];
#pragma unroll
    for (int dd = 0; dd < 16; dd++)
      acc[dd] += ctxs[(dg * 16 + dd) * 64 + e] * w;
  }
  unsigned short* base = ctx2t + (size_t)b * 1024 * 1024;
#pragma unroll
  for (int g = 0; g < 4; g++){
    int k = h * 64 + dg * 16 + g * 4;
    int kt = k >> 5, quad = (k >> 3) & 3, e0 = k & 7;
    size_t idx = ((size_t)(f >> 4) * 2048 + (size_t)kt * 64 + quad * 16 + (f & 15)) * 8 + e0;
    ushort4 o;
    o.x = f2bf(acc[g*4+0]); o.y = f2bf(acc[g*4+1]);
    o.z = f2bf(acc[g*4+2]); o.w = f2bf(acc[g*4+3]);
    *(ushort4*)&base[idx] = o;
  }
}

extern "C" void kernel_launch(void* const* d_in, const int* in_sizes, int n_in,
                              void* d_out, int out_size, void* d_ws, size_t ws_size,
                              hipStream_t stream) {
  const float* x     = (const float*)d_in[0];  // [4,4096,1024]
  const float* w_qkv = (const float*)d_in[1];  // [1024,3072]
  const float* w_out = (const float*)d_in[2];  // [1024,1024]
  const float* b_out = (const float*)d_in[3];  // [1024]
  float* out = (float*)d_out;                  // [4,4096,1024] fp32

  const int M = 4 * SEQ;  // 16384

  unsigned short* xb = (unsigned short*)d_out;  // dead before gemm_final writes

  char* wp = (char*)d_ws;
  size_t off = 0;
  auto nxt = [&](size_t bytes) -> char* {
    char* p = wp + off;
    off += (bytes + 255) & ~(size_t)255;
    return p;
  };
  unsigned short* wqkvT = (unsigned short*)nxt((size_t)3072 * 1024 * 2);   // 6 MiB
  unsigned short* qt    = (unsigned short*)nxt((size_t)64 * 64 * SEQ * 2); // 32 MiB
  unsigned short* kt    = (unsigned short*)nxt((size_t)64 * 64 * SEQ * 2); // 32 MiB
  unsigned short* vb    = (unsigned short*)nxt((size_t)M * 1024 * 2);      // 32 MiB
  float*          ctxp  = (float*)wqkvT;       // aliases wqkvT (dead after qkv_gemm)
  unsigned short* ctx2t = qt;                  // aliases qt (dead after ctx_partial)

  // 1. converts
  cvt_f32_bf16<<<(M * 1024) / 4 / 256, 256, 0, stream>>>((const float4*)x, (ushort4*)xb);
  transpose_cvt<<<dim3(3072 / 64, 1024 / 64), 256, 0, stream>>>(w_qkv, wqkvT, 1024, 3072);

  // 2. fused qkv GEMM (2-slot ring, 2 blocks/CU) -> qt, kt, vb
  qkv_gemm<<<768, 512, 0, stream>>>(xb, wqkvT, qt, kt, vb);

  // 3. context partials (fp32), 256 blocks
  ctx_partial<<<64 * 4, 256, 0, stream>>>(qt, kt, ctxp);

  // 4. ctx2 -> fragment-packed B for gemm_final
  ctx2_kernel<<<64 * 16, 256, 0, stream>>>(ctxp, w_out, ctx2t);

  // 5. final batched GEMM (A-LDS + packed-B mainloop, round-7)
  gemm_final<<<256, 512, 0, stream>>>(vb, ctx2t, out, b_out);
}

// Round 10
// 342.085 us; speedup vs baseline: 7.0963x; 7.0963x over previous
//
#include <hip/hip_runtime.h>
#include <hip/hip_bf16.h>

#define SEQ    4096
#define SCALE  0.125f

typedef __attribute__((ext_vector_type(8))) short s8v;
typedef __attribute__((ext_vector_type(8))) unsigned short u8v;
typedef __attribute__((ext_vector_type(4))) float f4v;

__device__ __forceinline__ unsigned short f2bf(float f){
  unsigned int u = __builtin_bit_cast(unsigned int, f);
  u += 0x7FFFu + ((u >> 16) & 1u);
  return (unsigned short)(u >> 16);
}

typedef const __attribute__((address_space(1))) unsigned int gl_uint;
typedef __attribute__((address_space(3))) unsigned int lds_uint;

__device__ __forceinline__ void gload_lds16(const unsigned short* g, unsigned short* l){
  __builtin_amdgcn_global_load_lds((gl_uint*)g, (lds_uint*)l, 16, 0, 0);
}

#define MM(a,b,c) __builtin_amdgcn_mfma_f32_16x16x32_bf16(a,b,c,0,0,0)
#define BAR() __builtin_amdgcn_s_barrier()
#define SB0() __builtin_amdgcn_sched_barrier(0)
#define LGKM0() do{ asm volatile("s_waitcnt lgkmcnt(0)" ::: "memory"); SB0(); }while(0)
#define VMW(n) asm volatile("s_waitcnt vmcnt(" #n ")" ::: "memory")

__device__ __forceinline__ void mfmaH0(const s8v (&A)[8], const s8v (&B)[4], f4v (&acc)[8][4]){
#pragma unroll
  for (int m = 0; m < 4; m++)
#pragma unroll
    for (int n = 0; n < 4; n++) acc[m][n] = MM(A[m], B[n], acc[m][n]);
}
__device__ __forceinline__ void mfmaH1(const s8v (&A)[8], const s8v (&B)[4], f4v (&acc)[8][4]){
#pragma unroll
  for (int m = 4; m < 8; m++)
#pragma unroll
    for (int n = 0; n < 4; n++) acc[m][n] = MM(A[m], B[n], acc[m][n]);
}

// ================ mainloop (2-SLOT ring, 64 KiB). With the compiler's natural
// 128-VGPR allocation this allows 2 blocks/CU (16 waves/CU) -- occupancy comes
// from ACTUAL resources, NOT from launch_bounds (R9 lesson: forcing min-waves=4
// capped VGPR at 128 < acc+frags and spilled acc to scratch: 8.3 GB HBM, 17x).
// Logic byte-identical to R9 (harness-verified correct).
__device__ __forceinline__ void mainloop_ab(
    const unsigned short* __restrict__ Ag,
    const unsigned short* __restrict__ Bg,
    int bm, int bn, f4v (&acc)[8][4])
{
  __shared__ __align__(16) unsigned short lds[32768];   // 64 KiB
  const int tid  = threadIdx.x;
  const int wave = tid >> 6, lane = tid & 63;
  const int quad = lane >> 4, l16 = lane & 15;
  const int wmi  = wave >> 2, wni = wave & 3;
  const char* ldsc = (const char*)lds;

  const int c16   = (quad ^ ((l16 >> 1) & 3)) * 16;     // byte chunk offset
  const int abase = (wmi * 128 + l16) * 64 + c16;       // bytes within slot
  const int bbase = 16384 + (wni * 64 + l16) * 64 + c16;

  const int schunk = (((tid & 3) ^ ((tid >> 3) & 3)) * 8);
  const unsigned short* aS = Ag + (size_t)(bm + (tid >> 2)) * 1024 + schunk;
  const unsigned short* bS = Bg + (size_t)(bn + (tid >> 2)) * 1024 + schunk;
  unsigned short* ldsw = lds + wave * 512;   // wave-uniform gload_lds base

#define STG_A(t_) do{ unsigned short* d_ = ldsw + ((t_) & 1) * 16384; \
    const unsigned short* s_ = aS + (t_) * 32; \
    gload_lds16(s_, d_); gload_lds16(s_ + 128 * 1024, d_ + 4096); }while(0)
#define STG_B(t_) do{ unsigned short* d_ = ldsw + ((t_) & 1) * 16384 + 8192; \
    const unsigned short* s_ = bS + (t_) * 32; \
    gload_lds16(s_, d_); gload_lds16(s_ + 128 * 1024, d_ + 4096); }while(0)

#define LD_B4(NB, base_) do{ \
    NB[0] = *(const s8v*)((base_) + bbase);        NB[1] = *(const s8v*)((base_) + bbase + 1024); \
    NB[2] = *(const s8v*)((base_) + bbase + 2048); NB[3] = *(const s8v*)((base_) + bbase + 3072); }while(0)
#define LD_A4LO(NA, base_) do{ \
    NA[0] = *(const s8v*)((base_) + abase);        NA[1] = *(const s8v*)((base_) + abase + 1024); \
    NA[2] = *(const s8v*)((base_) + abase + 2048); NA[3] = *(const s8v*)((base_) + abase + 3072); }while(0)
#define LD_A4HI(NA, base_) do{ \
    NA[4] = *(const s8v*)((base_) + abase + 4096); NA[5] = *(const s8v*)((base_) + abase + 5120); \
    NA[6] = *(const s8v*)((base_) + abase + 6144); NA[7] = *(const s8v*)((base_) + abase + 7168); }while(0)

  s8v A0[8], B0[4], A1[8], B1[4];

  // prologue: stage tiles 0,1 (8 ops); retire tile 0 (VMW(4)); read its frags
  STG_A(0); STG_B(0); STG_A(1); STG_B(1);
  VMW(4); BAR();
  LD_B4(B0, ldsc); LD_A4LO(A0, ldsc); LD_A4HI(A0, ldsc);

#define BODY(T_, CA, CB, NA, NB, DOSTG) do{ \
    LGKM0(); VMW(0); BAR(); SB0(); \
    if (DOSTG){ STG_A((T_) + 2); STG_B((T_) + 2); } \
    { const char* nb_ = ldsc + ((((T_) + 1) & 1) << 15); \
      LD_B4(NB, nb_); LD_A4LO(NA, nb_); \
      __builtin_amdgcn_s_setprio(1); mfmaH0(CA, CB, acc); __builtin_amdgcn_s_setprio(0); \
      LD_A4HI(NA, nb_); \
      __builtin_amdgcn_s_setprio(1); mfmaH1(CA, CB, acc); __builtin_amdgcn_s_setprio(0); } \
  }while(0)

  for (int t = 0; t < 30; t += 2){
    BODY(t,     A0, B0, A1, B1, 1);            // stages t+2 (<= 31)
    BODY(t + 1, A1, B1, A0, B0, (t + 1) <= 29);
  }
  BODY(30, A0, B0, A1, B1, 0);                 // reads frags(31)
  // tile 31 (frags in A1/B1; compiler inserts the lgkm wait)
  __builtin_amdgcn_s_setprio(1);
  mfmaH0(A1, B1, acc); mfmaH1(A1, B1, acc);
  __builtin_amdgcn_s_setprio(0);

#undef BODY
#undef LD_B4
#undef LD_A4LO
#undef LD_A4HI
#undef STG_A
#undef STG_B
}

// ================ mainloop variant 2 (round-7 verified on gemm_final):
// A-only LDS ring (64 KiB); B from global in fragment-packed layout.
__device__ __forceinline__ void mainloop_apk(
    const unsigned short* __restrict__ Ag,
    const unsigned short* __restrict__ Bpk,
    int bm, int bn, f4v (&acc)[8][4])
{
  __shared__ __align__(16) unsigned short lds[32768];   // 64 KiB, A-only
  const int tid  = threadIdx.x;
  const int wave = tid >> 6, lane = tid & 63;
  const int quad = lane >> 4, l16 = lane & 15;
  const int wmi  = wave >> 2, wni = wave & 3;
  const char* ldsc = (const char*)lds;

  const int c16   = (quad ^ ((l16 >> 1) & 3)) * 16;
  const int abase = (wmi * 128 + l16) * 64 + c16;

  const int schunk = (((tid & 3) ^ ((tid >> 3) & 3)) * 8);
  const unsigned short* aS = Ag + (size_t)(bm + (tid >> 2)) * 1024 + schunk;
  unsigned short* ldsw = lds + wave * 512;

  const unsigned short* bP = Bpk + ((size_t)((bn >> 4) + wni * 4) * 2048 + lane) * 8;

#define STG_A2(t_) do{ unsigned short* d_ = ldsw + ((t_) & 3) * 8192; \
    const unsigned short* s_ = aS + (t_) * 32; \
    gload_lds16(s_, d_); gload_lds16(s_ + 128 * 1024, d_ + 4096); }while(0)

#define LDB2(t_, BN) do{ \
    BN[0] = *(const s8v*)(bP +         (t_) * 512); \
    BN[1] = *(const s8v*)(bP + 16384 + (t_) * 512); \
    BN[2] = *(const s8v*)(bP + 32768 + (t_) * 512); \
    BN[3] = *(const s8v*)(bP + 49152 + (t_) * 512); }while(0)

#define LD2_A4LO(NA, base_) do{ const char* p_ = (base_); \
    NA[0] = *(const s8v*)(p_ + abase);        NA[1] = *(const s8v*)(p_ + abase + 1024); \
    NA[2] = *(const s8v*)(p_ + abase + 2048); NA[3] = *(const s8v*)(p_ + abase + 3072); }while(0)
#define LD2_A4HI(NA, base_) do{ const char* p_ = (base_); \
    NA[4] = *(const s8v*)(p_ + abase + 4096); NA[5] = *(const s8v*)(p_ + abase + 5120); \
    NA[6] = *(const s8v*)(p_ + abase + 6144); NA[7] = *(const s8v*)(p_ + abase + 7168); }while(0)

  s8v A0[8], B0[4], A1[8], B1[4];

  STG_A2(0); STG_A2(1); STG_A2(2);
  LDB2(0, B0);
  VMW(8); BAR();
  LD2_A4LO(A0, ldsc); LD2_A4HI(A0, ldsc);

#define BODY2(T_, CA, CB, NA, NB, DOSTG, DOLD) do{ \
    SB0(); VMW(6); BAR(); SB0(); \
    if (DOSTG) STG_A2((T_) + 3); \
    if (DOLD)  LDB2((T_) + 1, NB); \
    if (DOLD)  LD2_A4LO(NA, ldsc + ((((T_) + 1) & 3) << 14)); \
    __builtin_amdgcn_s_setprio(1); mfmaH0(CA, CB, acc); __builtin_amdgcn_s_setprio(0); \
    if (DOLD)  LD2_A4HI(NA, ldsc + ((((T_) + 1) & 3) << 14)); \
    __builtin_amdgcn_s_setprio(1); mfmaH1(CA, CB, acc); __builtin_amdgcn_s_setprio(0); \
  }while(0)

  for (int t = 0; t < 28; t += 2){
    BODY2(t,     A0, B0, A1, B1, 1, 1);
    BODY2(t + 1, A1, B1, A0, B0, 1, 1);
  }
  BODY2(28, A0, B0, A1, B1, 1, 1);
  BODY2(29, A1, B1, A0, B0, 0, 1);
  BODY2(30, A0, B0, A1, B1, 0, 1);
  BODY2(31, A1, B1, A0, B0, 0, 0);

#undef BODY2
#undef LD2_A4LO
#undef LD2_A4HI
#undef LDB2
#undef STG_A2
}

// ---------------- qkv GEMM (fused q-softmax + k-exp), 256x256 tile
__global__ __launch_bounds__(512, 2) void qkv_gemm(
    const unsigned short* __restrict__ A,
    const unsigned short* __restrict__ Bt,
    unsigned short* __restrict__ qt,
    unsigned short* __restrict__ kt,
    unsigned short* __restrict__ vb)
{
  const int id  = blockIdx.x;
  const int swz = (id & 7) * 96 + (id >> 3);     // 768 blocks, bijective XCD swizzle
  const int bm  = (swz / 12) * 256, bn = (swz % 12) * 256;

  f4v acc[8][4];
#pragma unroll
  for (int i = 0; i < 8; i++)
#pragma unroll
    for (int j = 0; j < 4; j++) acc[i][j] = (f4v){0.f,0.f,0.f,0.f};

  mainloop_ab(A, Bt, bm, bn, acc);

  const int tid = threadIdx.x;
  const int wave = tid >> 6, lane = tid & 63;
  const int quad = lane >> 4, l16 = lane & 15;
  const int wmi = wave >> 2, wni = wave & 3;
  const int colbase = bn + wni * 64;             // 64-aligned -> one head per wave
  const int rowbase = bm + wmi * 128;
  const int sec = colbase >> 10;                 // 0=q 1=k 2=v (wave-uniform)

  if (sec == 2){
#pragma unroll
    for (int nf = 0; nf < 4; nf++){
      int vc = colbase + nf * 16 + l16 - 2048;
#pragma unroll
      for (int mf = 0; mf < 8; mf++){
        int row = rowbase + mf * 16 + quad * 4;
#pragma unroll
        for (int r = 0; r < 4; r++)
          vb[(size_t)(row + r) * 1024 + vc] = f2bf(acc[mf][nf][r]);
      }
    }
    return;
  }

  if (sec == 0){
    // fused softmax over d (wave's 64 cols = full head)
#pragma unroll
    for (int mf = 0; mf < 8; mf++){
#pragma unroll
      for (int r = 0; r < 4; r++){
        float m = fmaxf(fmaxf(acc[mf][0][r], acc[mf][1][r]),
                        fmaxf(acc[mf][2][r], acc[mf][3][r]));
        for (int off = 8; off; off >>= 1) m = fmaxf(m, __shfl_xor(m, off));
        m *= SCALE;
        float e0 = __expf(acc[mf][0][r] * SCALE - m);
        float e1 = __expf(acc[mf][1][r] * SCALE - m);
        float e2 = __expf(acc[mf][2][r] * SCALE - m);
        float e3 = __expf(acc[mf][3][r] * SCALE - m);
        float s = (e0 + e1) + (e2 + e3);
        for (int off = 8; off; off >>= 1) s += __shfl_xor(s, off);
        float inv = 1.f / s;
        acc[mf][0][r] = e0 * inv; acc[mf][1][r] = e1 * inv;
        acc[mf][2][r] = e2 * inv; acc[mf][3][r] = e3 * inv;
      }
    }
#pragma unroll
    for (int nf = 0; nf < 4; nf++){
      int col = colbase + nf * 16 + l16;
      int h = (col >> 6) & 15, de = col & 63;
#pragma unroll
      for (int mf = 0; mf < 8; mf++){
        int row = rowbase + mf * 16 + quad * 4;
        int bb = row >> 12, nl = row & 4095;
        ushort4 o;
        o.x = f2bf(acc[mf][nf][0]); o.y = f2bf(acc[mf][nf][1]);
        o.z = f2bf(acc[mf][nf][2]); o.w = f2bf(acc[mf][nf][3]);
        *(ushort4*)&qt[(((size_t)bb * 16 + h) * 64 + de) * SEQ + nl] = o;
      }
    }
  } else {
    // k: exp per element; normalizer recovered in ctx2 (q cols sum to 1)
#pragma unroll
    for (int nf = 0; nf < 4; nf++){
      int col = colbase + nf * 16 + l16;
      int h = (col >> 6) & 15, de = col & 63;
#pragma unroll
      for (int mf = 0; mf < 8; mf++){
        int row = rowbase + mf * 16 + quad * 4;
        int bb = row >> 12, nl = row & 4095;
        ushort4 o;
        o.x = f2bf(__expf(acc[mf][nf][0])); o.y = f2bf(__expf(acc[mf][nf][1]));
        o.z = f2bf(__expf(acc[mf][nf][2])); o.w = f2bf(__expf(acc[mf][nf][3]));
        *(ushort4*)&kt[(((size_t)bb * 16 + h) * 64 + de) * SEQ + nl] = o;
      }
    }
  }
}

// ---------------- final batched GEMM: out[b] = vb[b] @ ctx2^T + bias (round-7 form)
__global__ __launch_bounds__(512, 2) void gemm_final(
    const unsigned short* __restrict__ A,
    const unsigned short* __restrict__ C2pk,
    float* __restrict__ Cf,
    const float* __restrict__ bias)
{
  const int id  = blockIdx.x;
  const int swz = (id & 7) * 32 + (id >> 3);     // 256 blocks, bijective XCD swizzle
  const int bm  = (swz >> 2) * 256, bn = (swz & 3) * 256;
  const unsigned short* Bpk = C2pk + (size_t)(bm >> 12) * 1024 * 1024;

  f4v acc[8][4];
#pragma unroll
  for (int i = 0; i < 8; i++)
#pragma unroll
    for (int j = 0; j < 4; j++) acc[i][j] = (f4v){0.f,0.f,0.f,0.f};

  mainloop_apk(A, Bpk, bm, bn, acc);

  const int tid = threadIdx.x;
  const int wave = tid >> 6, lane = tid & 63;
  const int quad = lane >> 4, l16 = lane & 15;
  const int wmi = wave >> 2, wni = wave & 3;

#pragma unroll
  for (int nf = 0; nf < 4; nf++){
    int col = bn + wni * 64 + nf * 16 + l16;
    float bv = bias[col];
#pragma unroll
    for (int mf = 0; mf < 8; mf++){
      int row = bm + wmi * 128 + mf * 16 + quad * 4;
#pragma unroll
      for (int r = 0; r < 4; r++)
        Cf[(size_t)(row + r) * 1024 + col] = acc[mf][nf][r] + bv;
    }
  }
}

// ---------------- fp32 -> bf16 elementwise (4/thread)
__global__ void cvt_f32_bf16(const float4* __restrict__ in, ushort4* __restrict__ outp){
  int i = blockIdx.x * 256 + threadIdx.x;
  float4 v = in[i];
  ushort4 o;
  o.x = f2bf(v.x); o.y = f2bf(v.y); o.z = f2bf(v.z); o.w = f2bf(v.w);
  outp[i] = o;
}

// ---------------- transpose + cvt: in[R,C] fp32 -> out[C,R] bf16  (for qkv's B^T)
__global__ __launch_bounds__(256) void transpose_cvt(const float* __restrict__ in,
                                                     unsigned short* __restrict__ outp,
                                                     int R, int C){
  __shared__ float tile[64][65];
  int r0 = blockIdx.y * 64, c0 = blockIdx.x * 64;
  int t = threadIdx.x;
  for (int i = t; i < 4096; i += 256){ int r = i >> 6, c = i & 63;
    tile[r][c] = in[(size_t)(r0 + r) * C + c0 + c]; }
  __syncthreads();
  for (int i = t; i < 4096; i += 256){ int c = i >> 6, r = i & 63;
    outp[(size_t)(c0 + c) * R + r0 + r] = f2bf(tile[r][c]); }
}

// ---------------- ctx partial: ctxp[bh*4+chunk][d*64+e] = sum_{n in chunk} qt[d,n] kt[e,n]
__global__ __launch_bounds__(256) void ctx_partial(const unsigned short* __restrict__ qt,
                                                   const unsigned short* __restrict__ kt,
                                                   float* __restrict__ ctxp){
  __shared__ float red[4096];
  int bh = blockIdx.x >> 2, ch = blockIdx.x & 3;
  int t = threadIdx.x, wave = t >> 6, lane = t & 63, quad = lane >> 4, l16 = lane & 15;
  const unsigned short* qb = qt + (size_t)bh * 64 * SEQ;
  const unsigned short* kb = kt + (size_t)bh * 64 * SEQ;
  f4v acc[4][4];
#pragma unroll
  for (int i = 0; i < 4; i++)
#pragma unroll
    for (int j = 0; j < 4; j++) acc[i][j] = (f4v){0.f,0.f,0.f,0.f};
  int ns = ch * 1024 + wave * 256;
  for (int n0 = ns; n0 < ns + 256; n0 += 32){
    s8v af[4], bf[4];
#pragma unroll
    for (int mt = 0; mt < 4; mt++) af[mt] = *(const s8v*)&qb[(size_t)(mt*16 + l16) * SEQ + n0 + quad*8];
#pragma unroll
    for (int nt = 0; nt < 4; nt++) bf[nt] = *(const s8v*)&kb[(size_t)(nt*16 + l16) * SEQ + n0 + quad*8];
#pragma unroll
    for (int mt = 0; mt < 4; mt++)
#pragma unroll
      for (int nt = 0; nt < 4; nt++)
        acc[mt][nt] = __builtin_amdgcn_mfma_f32_16x16x32_bf16(af[mt], bf[nt], acc[mt][nt], 0, 0, 0);
  }
  for (int i = t; i < 4096; i += 256) red[i] = 0.f;
  __syncthreads();
  for (int w = 0; w < 4; w++){
    if (wave == w){
#pragma unroll
      for (int mt = 0; mt < 4; mt++)
#pragma unroll
        for (int nt = 0; nt < 4; nt++)
#pragma unroll
          for (int r = 0; r < 4; r++)
            red[(mt*16 + quad*4 + r) * 64 + nt*16 + l16] += acc[mt][nt][r];
    }
    __syncthreads();
  }
  float* cp = ctxp + (size_t)blockIdx.x * 4096;
  for (int i = t; i < 4096; i += 256) cp[i] = red[i];
}

// ---------------- ctx2: fragment-packed B for gemm_final (round-7 form).
__global__ __launch_bounds__(256) void ctx2_kernel(const float* __restrict__ ctxp,
                                                   const float* __restrict__ w_out,
                                                   unsigned short* __restrict__ ctx2t){
  __shared__ float ctxs[4096];
  __shared__ float inv_s[64];
  int bh = blockIdx.x >> 4, fc = blockIdx.x & 15;
  int b = bh >> 4, h = bh & 15;
  int t = threadIdx.x;
  int fl = t & 63, dg = t >> 6;
  int f = fc * 64 + fl;
  for (int i = t; i < 4096; i += 256){
    const float* p = ctxp + (size_t)bh * 4 * 4096 + i;
    ctxs[i] = (p[0] + p[4096]) + (p[8192] + p[12288]);
  }
  __syncthreads();
  if (t < 64){
    float s = 0.f;
#pragma unroll
    for (int d = 0; d < 64; d++) s += ctxs[d * 64 + t];
    inv_s[t] = 1.f / s;
  }
  __syncthreads();
  float acc[16];
#pragma unroll
  for (int i = 0; i < 16; i++) acc[i] = 0.f;
  for (int e = 0; e < 64; e++){
    float w = w_out[(size_t)(h * 64 + e) * 1024 + f] * inv_s[e];
#pragma unroll
    for (int dd = 0; dd < 16; dd++)
      acc[dd] += ctxs[(dg * 16 + dd) * 64 + e] * w;
  }
  unsigned short* base = ctx2t + (size_t)b * 1024 * 1024;
#pragma unroll
  for (int g = 0; g < 4; g++){
    int k = h * 64 + dg * 16 + g * 4;
    int kt = k >> 5, quad = (k >> 3) & 3, e0 = k & 7;
    size_t idx = ((size_t)(f >> 4) * 2048 + (size_t)kt * 64 + quad * 16 + (f & 15)) * 8 + e0;
    ushort4 o;
    o.x = f2bf(acc[g*4+0]); o.y = f2bf(acc[g*4+1]);
    o.z = f2bf(acc[g*4+2]); o.w = f2bf(acc[g*4+3]);
    *(ushort4*)&base[idx] = o;
  }
}

extern "C" void kernel_launch(void* const* d_in, const int* in_sizes, int n_in,
                              void* d_out, int out_size, void* d_ws, size_t ws_size,
                              hipStream_t stream) {
  const float* x     = (const float*)d_in[0];  // [4,4096,1024]
  const float* w_qkv = (const float*)d_in[1];  // [1024,3072]
  const float* w_out = (const float*)d_in[2];  // [1024,1024]
  const float* b_out = (const float*)d_in[3];  // [1024]
  float* out = (float*)d_out;                  // [4,4096,1024] fp32

  const int M = 4 * SEQ;  // 16384

  unsigned short* xb = (unsigned short*)d_out;  // dead before gemm_final writes

  char* wp = (char*)d_ws;
  size_t off = 0;
  auto nxt = [&](size_t bytes) -> char* {
    char* p = wp + off;
    off += (bytes + 255) & ~(size_t)255;
    return p;
  };
  unsigned short* wqkvT = (unsigned short*)nxt((size_t)3072 * 1024 * 2);   // 6 MiB
  unsigned short* qt    = (unsigned short*)nxt((size_t)64 * 64 * SEQ * 2); // 32 MiB
  unsigned short* kt    = (unsigned short*)nxt((size_t)64 * 64 * SEQ * 2); // 32 MiB
  unsigned short* vb    = (unsigned short*)nxt((size_t)M * 1024 * 2);      // 32 MiB
  float*          ctxp  = (float*)wqkvT;       // aliases wqkvT (dead after qkv_gemm)
  unsigned short* ctx2t = qt;                  // aliases qt (dead after ctx_partial)

  // 1. converts
  cvt_f32_bf16<<<(M * 1024) / 4 / 256, 256, 0, stream>>>((const float4*)x, (ushort4*)xb);
  transpose_cvt<<<dim3(3072 / 64, 1024 / 64), 256, 0, stream>>>(w_qkv, wqkvT, 1024, 3072);

  // 2. fused qkv GEMM (2-slot ring, 64 KiB LDS -> 2 blocks/CU via natural VGPR=128)
  qkv_gemm<<<768, 512, 0, stream>>>(xb, wqkvT, qt, kt, vb);

  // 3. context partials (fp32), 256 blocks
  ctx_partial<<<64 * 4, 256, 0, stream>>>(qt, kt, ctxp);

  // 4. ctx2 -> fragment-packed B for gemm_final
  ctx2_kernel<<<64 * 16, 256, 0, stream>>>(ctxp, w_out, ctx2t);

  // 5. final batched GEMM (A-LDS + packed-B mainloop, round-7)
  gemm_final<<<256, 512, 0, stream>>>(vb, ctx2t, out, b_out);
}

// Round 11
// 336.179 us; speedup vs baseline: 7.2209x; 1.0176x over previous
//
#include <hip/hip_runtime.h>
#include <hip/hip_bf16.h>

#define SEQ    4096
#define SCALE  0.125f

typedef __attribute__((ext_vector_type(8))) short s8v;
typedef __attribute__((ext_vector_type(8))) unsigned short u8v;
typedef __attribute__((ext_vector_type(4))) float f4v;

__device__ __forceinline__ unsigned short f2bf(float f){
  unsigned int u = __builtin_bit_cast(unsigned int, f);
  u += 0x7FFFu + ((u >> 16) & 1u);
  return (unsigned short)(u >> 16);
}

typedef const __attribute__((address_space(1))) unsigned int gl_uint;
typedef __attribute__((address_space(3))) unsigned int lds_uint;

__device__ __forceinline__ void gload_lds16(const unsigned short* g, unsigned short* l){
  __builtin_amdgcn_global_load_lds((gl_uint*)g, (lds_uint*)l, 16, 0, 0);
}

#define MM(a,b,c) __builtin_amdgcn_mfma_f32_16x16x32_bf16(a,b,c,0,0,0)
#define BAR() __builtin_amdgcn_s_barrier()
#define SB0() __builtin_amdgcn_sched_barrier(0)
#define LGKM0() do{ asm volatile("s_waitcnt lgkmcnt(0)" ::: "memory"); SB0(); }while(0)
#define VMW(n) asm volatile("s_waitcnt vmcnt(" #n ")" ::: "memory")

// 16 MFMA: one m-quadrant (4 m-frags) x 4 n-frags
__device__ __forceinline__ void mfma16q(const s8v (&A)[4], const s8v (&B)[4], f4v (*acc)[4]){
#pragma unroll
  for (int m = 0; m < 4; m++)
#pragma unroll
    for (int n = 0; n < 4; n++) acc[m][n] = MM(A[m], B[n], acc[m][n]);
}

__device__ __forceinline__ void mfmaH0(const s8v (&A)[8], const s8v (&B)[4], f4v (&acc)[8][4]){
#pragma unroll
  for (int m = 0; m < 4; m++)
#pragma unroll
    for (int n = 0; n < 4; n++) acc[m][n] = MM(A[m], B[n], acc[m][n]);
}
__device__ __forceinline__ void mfmaH1(const s8v (&A)[8], const s8v (&B)[4], f4v (&acc)[8][4]){
#pragma unroll
  for (int m = 4; m < 8; m++)
#pragma unroll
    for (int n = 0; n < 4; n++) acc[m][n] = MM(A[m], B[n], acc[m][n]);
}

// ================ 8-PHASE mainloop (m201-template shape on the R8-proven layout):
// 4-slot ring (32 KB/slot: A 16K + B 16K), 128 KiB; swizzle/staging byte-identical
// to R8 (SQ_LDS_BANK_CONFLICT == 0, harness-verified).
// Per 32-K slot s, TWO phases, each {issue stage+ds_reads BEFORE barrier ->
// BAR -> lgkm0 -> setprio+16 MFMA -> BAR}; counted VMW(4) once per slot (phB),
// never 0 until the tail. Reads-before-barrier overlap other waves' MFMA window.
// Safety: stage X(s+2) overwrites slot s-2, whose reads were lgkm-drained >=2
// phases (4 barriers) earlier. Residency of slot s: phB(s-1)'s VMW(4) (out-
// standing = A(s+1),B(s+1) only) + its barriers precede phA(s)'s reads.
__device__ __forceinline__ void mainloop_8ph(
    const unsigned short* __restrict__ Ag,
    const unsigned short* __restrict__ Bg,
    int bm, int bn, f4v (&acc)[8][4])
{
  __shared__ __align__(16) unsigned short lds[65536];   // 128 KiB
  const int tid  = threadIdx.x;
  const int wave = tid >> 6, lane = tid & 63;
  const int quad = lane >> 4, l16 = lane & 15;
  const int wmi  = wave >> 2, wni = wave & 3;
  const char* ldsc = (const char*)lds;

  const int c16   = (quad ^ ((l16 >> 1) & 3)) * 16;     // verified swizzle
  const int abase = (wmi * 128 + l16) * 64 + c16;       // bytes within slot
  const int bbase = 16384 + (wni * 64 + l16) * 64 + c16;

  const int schunk = (((tid & 3) ^ ((tid >> 3) & 3)) * 8);
  const unsigned short* aS = Ag + (size_t)(bm + (tid >> 2)) * 1024 + schunk;
  const unsigned short* bS = Bg + (size_t)(bn + (tid >> 2)) * 1024 + schunk;
  unsigned short* ldsw = lds + wave * 512;   // wave-uniform gload_lds base

#define STG_A(t_) do{ unsigned short* d_ = ldsw + ((t_) & 3) * 16384; \
    const unsigned short* s_ = aS + (t_) * 32; \
    gload_lds16(s_, d_); gload_lds16(s_ + 128 * 1024, d_ + 4096); }while(0)
#define STG_B(t_) do{ unsigned short* d_ = ldsw + ((t_) & 3) * 16384 + 8192; \
    const unsigned short* s_ = bS + (t_) * 32; \
    gload_lds16(s_, d_); gload_lds16(s_ + 128 * 1024, d_ + 4096); }while(0)

  s8v Af[4], Bf[4];

#define RD_B(S_) do{ const char* p_ = ldsc + (((S_) & 3) << 15); \
    Bf[0] = *(const s8v*)(p_ + bbase);        Bf[1] = *(const s8v*)(p_ + bbase + 1024); \
    Bf[2] = *(const s8v*)(p_ + bbase + 2048); Bf[3] = *(const s8v*)(p_ + bbase + 3072); }while(0)
#define RD_A(S_, MH) do{ const char* p_ = ldsc + (((S_) & 3) << 15) + (MH) * 4096; \
    Af[0] = *(const s8v*)(p_ + abase);        Af[1] = *(const s8v*)(p_ + abase + 1024); \
    Af[2] = *(const s8v*)(p_ + abase + 2048); Af[3] = *(const s8v*)(p_ + abase + 3072); }while(0)

#define PHA(S_, STG_) do{ \
    if (STG_) STG_A((S_) + 2); \
    RD_B(S_); RD_A(S_, 0); \
    BAR(); LGKM0(); \
    __builtin_amdgcn_s_setprio(1); mfma16q(Af, Bf, &acc[0]); __builtin_amdgcn_s_setprio(0); \
    BAR(); }while(0)

#define PHB(S_, STG_, VW_) do{ \
    if (STG_) STG_B((S_) + 2); \
    RD_A(S_, 1); \
    VW_; \
    BAR(); LGKM0(); \
    __builtin_amdgcn_s_setprio(1); mfma16q(Af, Bf, &acc[4]); __builtin_amdgcn_s_setprio(0); \
    BAR(); }while(0)

  // prologue: stage slots 0,1 (8 ops); VMW(4) retires slot 0 (slot 1 in flight);
  // barrier collectivizes before phA(0)'s reads.
  STG_A(0); STG_B(0); STG_A(1); STG_B(1);
  VMW(4); BAR();

  for (int s = 0; s < 28; s += 4){
    PHA(s,     1); PHB(s,     1, VMW(4));
    PHA(s + 1, 1); PHB(s + 1, 1, VMW(4));
    PHA(s + 2, 1); PHB(s + 2, 1, VMW(4));
    PHA(s + 3, 1); PHB(s + 3, 1, VMW(4));
  }
  PHA(28, 1); PHB(28, 1, VMW(4));
  PHA(29, 1); PHB(29, 1, VMW(4));   // stages slot 31 (last)
  PHA(30, 0); PHB(30, 0, VMW(0));   // drain: slot 31 resident
  PHA(31, 0); PHB(31, 0, (void)0);

#undef PHA
#undef PHB
#undef RD_A
#undef RD_B
#undef STG_A
#undef STG_B
}

// ================ mainloop variant 2 (round-7 verified on gemm_final):
// A-only LDS ring (64 KiB); B from global in fragment-packed layout.
__device__ __forceinline__ void mainloop_apk(
    const unsigned short* __restrict__ Ag,
    const unsigned short* __restrict__ Bpk,
    int bm, int bn, f4v (&acc)[8][4])
{
  __shared__ __align__(16) unsigned short lds[32768];   // 64 KiB, A-only
  const int tid  = threadIdx.x;
  const int wave = tid >> 6, lane = tid & 63;
  const int quad = lane >> 4, l16 = lane & 15;
  const int wmi  = wave >> 2, wni = wave & 3;
  const char* ldsc = (const char*)lds;

  const int c16   = (quad ^ ((l16 >> 1) & 3)) * 16;
  const int abase = (wmi * 128 + l16) * 64 + c16;

  const int schunk = (((tid & 3) ^ ((tid >> 3) & 3)) * 8);
  const unsigned short* aS = Ag + (size_t)(bm + (tid >> 2)) * 1024 + schunk;
  unsigned short* ldsw = lds + wave * 512;

  const unsigned short* bP = Bpk + ((size_t)((bn >> 4) + wni * 4) * 2048 + lane) * 8;

#define STG_A2(t_) do{ unsigned short* d_ = ldsw + ((t_) & 3) * 8192; \
    const unsigned short* s_ = aS + (t_) * 32; \
    gload_lds16(s_, d_); gload_lds16(s_ + 128 * 1024, d_ + 4096); }while(0)

#define LDB2(t_, BN) do{ \
    BN[0] = *(const s8v*)(bP +         (t_) * 512); \
    BN[1] = *(const s8v*)(bP + 16384 + (t_) * 512); \
    BN[2] = *(const s8v*)(bP + 32768 + (t_) * 512); \
    BN[3] = *(const s8v*)(bP + 49152 + (t_) * 512); }while(0)

#define LD2_A4LO(NA, base_) do{ const char* p_ = (base_); \
    NA[0] = *(const s8v*)(p_ + abase);        NA[1] = *(const s8v*)(p_ + abase + 1024); \
    NA[2] = *(const s8v*)(p_ + abase + 2048); NA[3] = *(const s8v*)(p_ + abase + 3072); }while(0)
#define LD2_A4HI(NA, base_) do{ const char* p_ = (base_); \
    NA[4] = *(const s8v*)(p_ + abase + 4096); NA[5] = *(const s8v*)(p_ + abase + 5120); \
    NA[6] = *(const s8v*)(p_ + abase + 6144); NA[7] = *(const s8v*)(p_ + abase + 7168); }while(0)

  s8v A0[8], B0[4], A1[8], B1[4];

  STG_A2(0); STG_A2(1); STG_A2(2);
  LDB2(0, B0);
  VMW(8); BAR();
  LD2_A4LO(A0, ldsc); LD2_A4HI(A0, ldsc);

#define BODY2(T_, CA, CB, NA, NB, DOSTG, DOLD) do{ \
    SB0(); VMW(6); BAR(); SB0(); \
    if (DOSTG) STG_A2((T_) + 3); \
    if (DOLD)  LDB2((T_) + 1, NB); \
    if (DOLD)  LD2_A4LO(NA, ldsc + ((((T_) + 1) & 3) << 14)); \
    __builtin_amdgcn_s_setprio(1); mfmaH0(CA, CB, acc); __builtin_amdgcn_s_setprio(0); \
    if (DOLD)  LD2_A4HI(NA, ldsc + ((((T_) + 1) & 3) << 14)); \
    __builtin_amdgcn_s_setprio(1); mfmaH1(CA, CB, acc); __builtin_amdgcn_s_setprio(0); \
  }while(0)

  for (int t = 0; t < 28; t += 2){
    BODY2(t,     A0, B0, A1, B1, 1, 1);
    BODY2(t + 1, A1, B1, A0, B0, 1, 1);
  }
  BODY2(28, A0, B0, A1, B1, 1, 1);
  BODY2(29, A1, B1, A0, B0, 0, 1);
  BODY2(30, A0, B0, A1, B1, 0, 1);
  BODY2(31, A1, B1, A0, B0, 0, 0);

#undef BODY2
#undef LD2_A4LO
#undef LD2_A4HI
#undef LDB2
#undef STG_A2
}

// ---------------- qkv GEMM (fused q-softmax + k-exp), 256x256 tile, 8-phase
__global__ __launch_bounds__(512, 2) void qkv_gemm(
    const unsigned short* __restrict__ A,
    const unsigned short* __restrict__ Bt,
    unsigned short* __restrict__ qt,
    unsigned short* __restrict__ kt,
    unsigned short* __restrict__ vb)
{
  const int id  = blockIdx.x;
  const int swz = (id & 7) * 96 + (id >> 3);     // 768 blocks, bijective XCD swizzle
  const int bm  = (swz / 12) * 256, bn = (swz % 12) * 256;

  f4v acc[8][4];
#pragma unroll
  for (int i = 0; i < 8; i++)
#pragma unroll
    for (int j = 0; j < 4; j++) acc[i][j] = (f4v){0.f,0.f,0.f,0.f};

  mainloop_8ph(A, Bt, bm, bn, acc);

  const int tid = threadIdx.x;
  const int wave = tid >> 6, lane = tid & 63;
  const int quad = lane >> 4, l16 = lane & 15;
  const int wmi = wave >> 2, wni = wave & 3;
  const int colbase = bn + wni * 64;             // 64-aligned -> one head per wave
  const int rowbase = bm + wmi * 128;
  const int sec = colbase >> 10;                 // 0=q 1=k 2=v (wave-uniform)

  if (sec == 2){
#pragma unroll
    for (int nf = 0; nf < 4; nf++){
      int vc = colbase + nf * 16 + l16 - 2048;
#pragma unroll
      for (int mf = 0; mf < 8; mf++){
        int row = rowbase + mf * 16 + quad * 4;
#pragma unroll
        for (int r = 0; r < 4; r++)
          vb[(size_t)(row + r) * 1024 + vc] = f2bf(acc[mf][nf][r]);
      }
    }
    return;
  }

  if (sec == 0){
    // fused softmax over d (wave's 64 cols = full head)
#pragma unroll
    for (int mf = 0; mf < 8; mf++){
#pragma unroll
      for (int r = 0; r < 4; r++){
        float m = fmaxf(fmaxf(acc[mf][0][r], acc[mf][1][r]),
                        fmaxf(acc[mf][2][r], acc[mf][3][r]));
        for (int off = 8; off; off >>= 1) m = fmaxf(m, __shfl_xor(m, off));
        m *= SCALE;
        float e0 = __expf(acc[mf][0][r] * SCALE - m);
        float e1 = __expf(acc[mf][1][r] * SCALE - m);
        float e2 = __expf(acc[mf][2][r] * SCALE - m);
        float e3 = __expf(acc[mf][3][r] * SCALE - m);
        float s = (e0 + e1) + (e2 + e3);
        for (int off = 8; off; off >>= 1) s += __shfl_xor(s, off);
        float inv = 1.f / s;
        acc[mf][0][r] = e0 * inv; acc[mf][1][r] = e1 * inv;
        acc[mf][2][r] = e2 * inv; acc[mf][3][r] = e3 * inv;
      }
    }
#pragma unroll
    for (int nf = 0; nf < 4; nf++){
      int col = colbase + nf * 16 + l16;
      int h = (col >> 6) & 15, de = col & 63;
#pragma unroll
      for (int mf = 0; mf < 8; mf++){
        int row = rowbase + mf * 16 + quad * 4;
        int bb = row >> 12, nl = row & 4095;
        ushort4 o;
        o.x = f2bf(acc[mf][nf][0]); o.y = f2bf(acc[mf][nf][1]);
        o.z = f2bf(acc[mf][nf][2]); o.w = f2bf(acc[mf][nf][3]);
        *(ushort4*)&qt[(((size_t)bb * 16 + h) * 64 + de) * SEQ + nl] = o;
      }
    }
  } else {
    // k: exp per element; normalizer recovered in ctx2 (q cols sum to 1)
#pragma unroll
    for (int nf = 0; nf < 4; nf++){
      int col = colbase + nf * 16 + l16;
      int h = (col >> 6) & 15, de = col & 63;
#pragma unroll
      for (int mf = 0; mf < 8; mf++){
        int row = rowbase + mf * 16 + quad * 4;
        int bb = row >> 12, nl = row & 4095;
        ushort4 o;
        o.x = f2bf(__expf(acc[mf][nf][0])); o.y = f2bf(__expf(acc[mf][nf][1]));
        o.z = f2bf(__expf(acc[mf][nf][2])); o.w = f2bf(__expf(acc[mf][nf][3]));
        *(ushort4*)&kt[(((size_t)bb * 16 + h) * 64 + de) * SEQ + nl] = o;
      }
    }
  }
}

// ---------------- final batched GEMM: out[b] = vb[b] @ ctx2^T + bias (round-7 form)
__global__ __launch_bounds__(512, 2) void gemm_final(
    const unsigned short* __restrict__ A,
    const unsigned short* __restrict__ C2pk,
    float* __restrict__ Cf,
    const float* __restrict__ bias)
{
  const int id  = blockIdx.x;
  const int swz = (id & 7) * 32 + (id >> 3);     // 256 blocks, bijective XCD swizzle
  const int bm  = (swz >> 2) * 256, bn = (swz & 3) * 256;
  const unsigned short* Bpk = C2pk + (size_t)(bm >> 12) * 1024 * 1024;

  f4v acc[8][4];
#pragma unroll
  for (int i = 0; i < 8; i++)
#pragma unroll
    for (int j = 0; j < 4; j++) acc[i][j] = (f4v){0.f,0.f,0.f,0.f};

  mainloop_apk(A, Bpk, bm, bn, acc);

  const int tid = threadIdx.x;
  const int wave = tid >> 6, lane = tid & 63;
  const int quad = lane >> 4, l16 = lane & 15;
  const int wmi = wave >> 2, wni = wave & 3;

#pragma unroll
  for (int nf = 0; nf < 4; nf++){
    int col = bn + wni * 64 + nf * 16 + l16;
    float bv = bias[col];
#pragma unroll
    for (int mf = 0; mf < 8; mf++){
      int row = bm + wmi * 128 + mf * 16 + quad * 4;
#pragma unroll
      for (int r = 0; r < 4; r++)
        Cf[(size_t)(row + r) * 1024 + col] = acc[mf][nf][r] + bv;
    }
  }
}

// ---------------- fp32 -> bf16 elementwise (4/thread)
__global__ void cvt_f32_bf16(const float4* __restrict__ in, ushort4* __restrict__ outp){
  int i = blockIdx.x * 256 + threadIdx.x;
  float4 v = in[i];
  ushort4 o;
  o.x = f2bf(v.x); o.y = f2bf(v.y); o.z = f2bf(v.z); o.w = f2bf(v.w);
  outp[i] = o;
}

// ---------------- transpose + cvt: in[R,C] fp32 -> out[C,R] bf16  (for qkv's B^T)
__global__ __launch_bounds__(256) void transpose_cvt(const float* __restrict__ in,
                                                     unsigned short* __restrict__ outp,
                                                     int R, int C){
  __shared__ float tile[64][65];
  int r0 = blockIdx.y * 64, c0 = blockIdx.x * 64;
  int t = threadIdx.x;
  for (int i = t; i < 4096; i += 256){ int r = i >> 6, c = i & 63;
    tile[r][c] = in[(size_t)(r0 + r) * C + c0 + c]; }
  __syncthreads();
  for (int i = t; i < 4096; i += 256){ int c = i >> 6, r = i & 63;
    outp[(size_t)(c0 + c) * R + r0 + r] = f2bf(tile[r][c]); }
}

// ---------------- ctx partial: ctxp[bh*4+chunk][d*64+e] = sum_{n in chunk} qt[d,n] kt[e,n]
__global__ __launch_bounds__(256) void ctx_partial(const unsigned short* __restrict__ qt,
                                                   const unsigned short* __restrict__ kt,
                                                   float* __restrict__ ctxp){
  __shared__ float red[4096];
  int bh = blockIdx.x >> 2, ch = blockIdx.x & 3;
  int t = threadIdx.x, wave = t >> 6, lane = t & 63, quad = lane >> 4, l16 = lane & 15;
  const unsigned short* qb = qt + (size_t)bh * 64 * SEQ;
  const unsigned short* kb = kt + (size_t)bh * 64 * SEQ;
  f4v acc[4][4];
#pragma unroll
  for (int i = 0; i < 4; i++)
#pragma unroll
    for (int j = 0; j < 4; j++) acc[i][j] = (f4v){0.f,0.f,0.f,0.f};
  int ns = ch * 1024 + wave * 256;
  for (int n0 = ns; n0 < ns + 256; n0 += 32){
    s8v af[4], bf[4];
#pragma unroll
    for (int mt = 0; mt < 4; mt++) af[mt] = *(const s8v*)&qb[(size_t)(mt*16 + l16) * SEQ + n0 + quad*8];
#pragma unroll
    for (int nt = 0; nt < 4; nt++) bf[nt] = *(const s8v*)&kb[(size_t)(nt*16 + l16) * SEQ + n0 + quad*8];
#pragma unroll
    for (int mt = 0; mt < 4; mt++)
#pragma unroll
      for (int nt = 0; nt < 4; nt++)
        acc[mt][nt] = __builtin_amdgcn_mfma_f32_16x16x32_bf16(af[mt], bf[nt], acc[mt][nt], 0, 0, 0);
  }
  for (int i = t; i < 4096; i += 256) red[i] = 0.f;
  __syncthreads();
  for (int w = 0; w < 4; w++){
    if (wave == w){
#pragma unroll
      for (int mt = 0; mt < 4; mt++)
#pragma unroll
        for (int nt = 0; nt < 4; nt++)
#pragma unroll
          for (int r = 0; r < 4; r++)
            red[(mt*16 + quad*4 + r) * 64 + nt*16 + l16] += acc[mt][nt][r];
    }
    __syncthreads();
  }
  float* cp = ctxp + (size_t)blockIdx.x * 4096;
  for (int i = t; i < 4096; i += 256) cp[i] = red[i];
}

// ---------------- ctx2: fragment-packed B for gemm_final (round-7 form).
__global__ __launch_bounds__(256) void ctx2_kernel(const float* __restrict__ ctxp,
                                                   const float* __restrict__ w_out,
                                                   unsigned short* __restrict__ ctx2t){
  __shared__ float ctxs[4096];
  __shared__ float inv_s[64];
  int bh = blockIdx.x >> 4, fc = blockIdx.x & 15;
  int b = bh >> 4, h = bh & 15;
  int t = threadIdx.x;
  int fl = t & 63, dg = t >> 6;
  int f = fc * 64 + fl;
  for (int i = t; i < 4096; i += 256){
    const float* p = ctxp + (size_t)bh * 4 * 4096 + i;
    ctxs[i] = (p[0] + p[4096]) + (p[8192] + p[12288]);
  }
  __syncthreads();
  if (t < 64){
    float s = 0.f;
#pragma unroll
    for (int d = 0; d < 64; d++) s += ctxs[d * 64 + t];
    inv_s[t] = 1.f / s;
  }
  __syncthreads();
  float acc[16];
#pragma unroll
  for (int i = 0; i < 16; i++) acc[i] = 0.f;
  for (int e = 0; e < 64; e++){
    float w = w_out[(size_t)(h * 64 + e) * 1024 + f] * inv_s[e];
#pragma unroll
    for (int dd = 0; dd < 16; dd++)
      acc[dd] += ctxs[(dg * 16 + dd) * 64 + e] * w;
  }
  unsigned short* base = ctx2t + (size_t)b * 1024 * 1024;
#pragma unroll
  for (int g = 0; g < 4; g++){
    int k = h * 64 + dg * 16 + g * 4;
    int kt = k >> 5, quad = (k >> 3) & 3, e0 = k & 7;
    size_t idx = ((size_t)(f >> 4) * 2048 + (size_t)kt * 64 + quad * 16 + (f & 15)) * 8 + e0;
    ushort4 o;
    o.x = f2bf(acc[g*4+0]); o.y = f2bf(acc[g*4+1]);
    o.z = f2bf(acc[g*4+2]); o.w = f2bf(acc[g*4+3]);
    *(ushort4*)&base[idx] = o;
  }
}

extern "C" void kernel_launch(void* const* d_in, const int* in_sizes, int n_in,
                              void* d_out, int out_size, void* d_ws, size_t ws_size,
                              hipStream_t stream) {
  const float* x     = (const float*)d_in[0];  // [4,4096,1024]
  const float* w_qkv = (const float*)d_in[1];  // [1024,3072]
  const float* w_out = (const float*)d_in[2];  // [1024,1024]
  const float* b_out = (const float*)d_in[3];  // [1024]
  float* out = (float*)d_out;                  // [4,4096,1024] fp32

  const int M = 4 * SEQ;  // 16384

  unsigned short* xb = (unsigned short*)d_out;  // dead before gemm_final writes

  char* wp = (char*)d_ws;
  size_t off = 0;
  auto nxt = [&](size_t bytes) -> char* {
    char* p = wp + off;
    off += (bytes + 255) & ~(size_t)255;
    return p;
  };
  unsigned short* wqkvT = (unsigned short*)nxt((size_t)3072 * 1024 * 2);   // 6 MiB
  unsigned short* qt    = (unsigned short*)nxt((size_t)64 * 64 * SEQ * 2); // 32 MiB
  unsigned short* kt    = (unsigned short*)nxt((size_t)64 * 64 * SEQ * 2); // 32 MiB
  unsigned short* vb    = (unsigned short*)nxt((size_t)M * 1024 * 2);      // 32 MiB
  float*          ctxp  = (float*)wqkvT;       // aliases wqkvT (dead after qkv_gemm)
  unsigned short* ctx2t = qt;                  // aliases qt (dead after ctx_partial)

  // 1. converts
  cvt_f32_bf16<<<(M * 1024) / 4 / 256, 256, 0, stream>>>((const float4*)x, (ushort4*)xb);
  transpose_cvt<<<dim3(3072 / 64, 1024 / 64), 256, 0, stream>>>(w_qkv, wqkvT, 1024, 3072);

  // 2. fused qkv GEMM (8-phase schedule on R8-proven 4-slot ring) -> qt, kt, vb
  qkv_gemm<<<768, 512, 0, stream>>>(xb, wqkvT, qt, kt, vb);

  // 3. context partials (fp32), 256 blocks
  ctx_partial<<<64 * 4, 256, 0, stream>>>(qt, kt, ctxp);

  // 4. ctx2 -> fragment-packed B for gemm_final
  ctx2_kernel<<<64 * 16, 256, 0, stream>>>(ctxp, w_out, ctx2t);

  // 5. final batched GEMM (A-LDS + packed-B mainloop, round-7)
  gemm_final<<<256, 512, 0, stream>>>(vb, ctx2t, out, b_out);
}